// Round 1
// baseline (3387.217 us; speedup 1.0000x reference)
//
#include <hip/hip_runtime.h>
#include <math.h>

#define NB 8
#define NN 1024
#define DD 512

// ---------------- score projection: si[b,i] = x[b,i,:] . w[:D], sj = x . w[D:] ----
__global__ __launch_bounds__(256) void score_proj_kernel(
    const float* __restrict__ x, const float* __restrict__ w,
    float* __restrict__ si, float* __restrict__ sj)
{
    int wave = threadIdx.x >> 6;
    int lane = threadIdx.x & 63;
    int row = blockIdx.x * 4 + wave;        // 0..8191  (b*N + i)
    const float4* xr = (const float4*)(x + (size_t)row * DD) + lane * 2;
    const float4* w1 = (const float4*)(w) + lane * 2;
    const float4* w2 = (const float4*)(w + DD) + lane * 2;
    float a = 0.f, b2 = 0.f;
#pragma unroll
    for (int c = 0; c < 2; ++c) {
        float4 xv = xr[c], wa = w1[c], wb = w2[c];
        a  += xv.x * wa.x + xv.y * wa.y + xv.z * wa.z + xv.w * wa.w;
        b2 += xv.x * wb.x + xv.y * wb.y + xv.z * wb.z + xv.w * wb.w;
    }
#pragma unroll
    for (int off = 32; off > 0; off >>= 1) {
        a  += __shfl_xor(a, off);
        b2 += __shfl_xor(b2, off);
    }
    if (lane == 0) { si[row] = a; sj[row] = b2; }
}

// ---------------- attention: scores -> softmax -> agg, out = x + agg -------------
__global__ __launch_bounds__(256) void attn_agg_kernel(
    const float* __restrict__ x, const int* __restrict__ adj,
    const float* __restrict__ si, const float* __restrict__ sj,
    const float* __restrict__ attn_b, float* __restrict__ out)
{
    const int TI = 8;
    __shared__ float sc[TI][NN];            // 32 KB
    int b  = blockIdx.x >> 7;               // / (N/TI=128)
    int i0 = (blockIdx.x & 127) * TI;
    int tid = threadIdx.x;
    float bb = attn_b[0];

    const int*   adjb = adj + ((size_t)b * NN + i0) * NN;
    const float* sib  = si + (size_t)b * NN + i0;
    const float* sjb  = sj + (size_t)b * NN;

    // pass 1: scores (LeakyReLU then mask)
    for (int idx = tid; idx < TI * NN; idx += 256) {
        int r = idx >> 10, j = idx & 1023;
        float s = sib[r] + sjb[j] + bb;
        s = (s >= 0.f) ? s : 0.2f * s;
        bool ok = (adjb[(size_t)r * NN + j] > 0) || (i0 + r == j);
        sc[r][j] = ok ? s : -INFINITY;
    }
    __syncthreads();

    // pass 2: softmax per row (32 threads / row)
    int r = tid >> 5, l32 = tid & 31;
    float m = -INFINITY;
    for (int j = l32; j < NN; j += 32) m = fmaxf(m, sc[r][j]);
#pragma unroll
    for (int off = 16; off > 0; off >>= 1) m = fmaxf(m, __shfl_xor(m, off, 32));
    float sum = 0.f;
    for (int j = l32; j < NN; j += 32) {
        float p = __expf(sc[r][j] - m);
        sc[r][j] = p;
        sum += p;
    }
#pragma unroll
    for (int off = 16; off > 0; off >>= 1) sum += __shfl_xor(sum, off, 32);
    float inv = 1.f / sum;
    for (int j = l32; j < NN; j += 32) sc[r][j] *= inv;
    __syncthreads();

    // pass 3: agg over j; thread owns row r, dims [l32*16, l32*16+16)
    float acc[16];
#pragma unroll
    for (int c = 0; c < 16; ++c) acc[c] = 0.f;
    const float* xb = x + (size_t)b * NN * DD;
    for (int j = 0; j < NN; ++j) {
        float wgt = sc[r][j];
        if (wgt != 0.f) {
            const float4* xr = (const float4*)(xb + (size_t)j * DD) + l32 * 4;
            float4 a0 = xr[0], a1 = xr[1], a2 = xr[2], a3 = xr[3];
            acc[0]  += wgt * a0.x; acc[1]  += wgt * a0.y; acc[2]  += wgt * a0.z; acc[3]  += wgt * a0.w;
            acc[4]  += wgt * a1.x; acc[5]  += wgt * a1.y; acc[6]  += wgt * a1.z; acc[7]  += wgt * a1.w;
            acc[8]  += wgt * a2.x; acc[9]  += wgt * a2.y; acc[10] += wgt * a2.z; acc[11] += wgt * a2.w;
            acc[12] += wgt * a3.x; acc[13] += wgt * a3.y; acc[14] += wgt * a3.z; acc[15] += wgt * a3.w;
        }
    }
    const float4* xi = (const float4*)(xb + (size_t)(i0 + r) * DD) + l32 * 4;
    float4* op = (float4*)(out + ((size_t)b * NN + i0 + r) * DD) + l32 * 4;
#pragma unroll
    for (int c = 0; c < 4; ++c) {
        float4 xv = xi[c];
        float4 o;
        o.x = acc[c * 4 + 0] + xv.x;
        o.y = acc[c * 4 + 1] + xv.y;
        o.z = acc[c * 4 + 2] + xv.z;
        o.w = acc[c * 4 + 3] + xv.w;
        op[c] = o;
    }
}

// ---------------- layernorm over D=512, one row per block ------------------------
__global__ __launch_bounds__(256) void ln_kernel(
    const float* __restrict__ in, const float* __restrict__ g,
    const float* __restrict__ be, float* __restrict__ out)
{
    int row = blockIdx.x;
    int tid = threadIdx.x;
    const float2* rp = (const float2*)(in + (size_t)row * DD);
    float2 v = rp[tid];
    float s  = v.x + v.y;
    float ss = v.x * v.x + v.y * v.y;
#pragma unroll
    for (int off = 32; off > 0; off >>= 1) {
        s  += __shfl_xor(s, off);
        ss += __shfl_xor(ss, off);
    }
    __shared__ float sh[8];
    int wave = tid >> 6, lane = tid & 63;
    if (lane == 0) { sh[wave] = s; sh[4 + wave] = ss; }
    __syncthreads();
    float S  = sh[0] + sh[1] + sh[2] + sh[3];
    float SS = sh[4] + sh[5] + sh[6] + sh[7];
    float mean = S * (1.f / DD);
    float var  = SS * (1.f / DD) - mean * mean;
    var = fmaxf(var, 0.f);
    float rs = rsqrtf(var + 1e-5f);
    float2 gv = ((const float2*)g)[tid];
    float2 bv = ((const float2*)be)[tid];
    float2 o;
    o.x = (v.x - mean) * rs * gv.x + bv.x;
    o.y = (v.y - mean) * rs * bv.y * 0.f + (v.y - mean) * rs * gv.y + bv.y; // see below
    // (rewritten cleanly)
    o.y = (v.y - mean) * rs * gv.y + bv.y;
    ((float2*)(out + (size_t)row * DD))[tid] = o;
}

__device__ __forceinline__ float gelu_exact(float v) {
    return 0.5f * v * (1.0f + erff(v * 0.70710678118654752f));
}

// ---------------- fp32 tiled GEMM: C = act(A@W + bias) [+ res] -------------------
// BM=BN=64, BK=16, 256 threads, 4x4 microtile.
template <bool GELU, bool RES>
__global__ __launch_bounds__(256) void gemm_kernel(
    const float* __restrict__ A, const float* __restrict__ W,
    const float* __restrict__ bias, const float* __restrict__ res,
    float* __restrict__ C, int M, int K, int Nn)
{
    __shared__ float As[16][68];
    __shared__ float Bs[16][68];
    int tid = threadIdx.x;
    int tx = tid & 15, ty = tid >> 4;
    int m0 = blockIdx.y * 64, n0 = blockIdx.x * 64;
    float acc[4][4];
#pragma unroll
    for (int i = 0; i < 4; ++i)
#pragma unroll
        for (int j = 0; j < 4; ++j) acc[i][j] = 0.f;

    int arow = tid >> 2;            // 0..63
    int akg  = (tid & 3) * 4;       // 0,4,8,12
    int brow = tid >> 4;            // 0..15
    int bcol = (tid & 15) * 4;

    for (int k0 = 0; k0 < K; k0 += 16) {
        float4 av = *(const float4*)(A + (size_t)(m0 + arow) * K + k0 + akg);
        As[akg + 0][arow] = av.x;
        As[akg + 1][arow] = av.y;
        As[akg + 2][arow] = av.z;
        As[akg + 3][arow] = av.w;
        *(float4*)&Bs[brow][bcol] = *(const float4*)(W + (size_t)(k0 + brow) * Nn + n0 + bcol);
        __syncthreads();
#pragma unroll
        for (int kk = 0; kk < 16; ++kk) {
            float4 a = *(const float4*)&As[kk][ty * 4];
            float4 b = *(const float4*)&Bs[kk][tx * 4];
            float ar[4] = {a.x, a.y, a.z, a.w};
            float br[4] = {b.x, b.y, b.z, b.w};
#pragma unroll
            for (int i = 0; i < 4; ++i)
#pragma unroll
                for (int j = 0; j < 4; ++j) acc[i][j] += ar[i] * br[j];
        }
        __syncthreads();
    }

#pragma unroll
    for (int i = 0; i < 4; ++i) {
        int row = m0 + ty * 4 + i;
#pragma unroll
        for (int j = 0; j < 4; ++j) {
            int col = n0 + tx * 4 + j;
            float v = acc[i][j] + bias[col];
            if (GELU) v = gelu_exact(v);
            if (RES)  v += res[(size_t)row * Nn + col];
            C[(size_t)row * Nn + col] = v;
        }
    }
}

extern "C" void kernel_launch(void* const* d_in, const int* in_sizes, int n_in,
                              void* d_out, int out_size, void* d_ws, size_t ws_size,
                              hipStream_t stream) {
    const float* nf     = (const float*)d_in[0];
    const int*   adj    = (const int*)d_in[1];
    const float* attn_w = (const float*)d_in[2];
    const float* attn_b = (const float*)d_in[3];
    const float* W1     = (const float*)d_in[4];
    const float* b1     = (const float*)d_in[5];
    const float* W2     = (const float*)d_in[6];
    const float* b2     = (const float*)d_in[7];
    const float* g1     = (const float*)d_in[8];
    const float* be1    = (const float*)d_in[9];
    const float* g2     = (const float*)d_in[10];
    const float* be2    = (const float*)d_in[11];
    float* out = (float*)d_out;

    float* ws    = (float*)d_ws;
    float* x_cur = ws;                   // 4,194,304 floats
    float* h     = ws + 4194304;         // 4,194,304
    float* si    = ws + 8388608;         // 8192
    float* sj    = ws + 8396800;         // 8192
    float* mid   = ws + 8404992;         // 16,777,216
    float* hres  = mid;                  // alias: dead before mid is written

    for (int l = 0; l < 3; ++l) {
        const float* xin = (l == 0) ? nf : x_cur;
        score_proj_kernel<<<2048, 256, 0, stream>>>(xin, attn_w + (size_t)l * 1024, si, sj);
        attn_agg_kernel<<<1024, 256, 0, stream>>>(xin, adj, si, sj, attn_b + l, hres);
        ln_kernel<<<8192, 256, 0, stream>>>(hres, g1 + (size_t)l * 512, be1 + (size_t)l * 512, h);
        gemm_kernel<true, false><<<dim3(32, 128), 256, 0, stream>>>(
            h, W1 + (size_t)l * 512 * 2048, b1 + (size_t)l * 2048, nullptr, mid, 8192, 512, 2048);
        gemm_kernel<false, true><<<dim3(8, 128), 256, 0, stream>>>(
            mid, W2 + (size_t)l * 2048 * 512, b2 + (size_t)l * 512, h, x_cur, 8192, 2048, 512);
        float* lnout = (l == 2) ? out : x_cur;
        ln_kernel<<<8192, 256, 0, stream>>>(x_cur, g2 + (size_t)l * 512, be2 + (size_t)l * 512, lnout);
    }
}

// Round 2
// 681.012 us; speedup vs baseline: 4.9738x; 4.9738x over previous
//
#include <hip/hip_runtime.h>
#include <math.h>

#define NB 8
#define NN 1024
#define DD 512

typedef unsigned short u16;
typedef unsigned int u32;
typedef unsigned long long u64;
typedef __attribute__((ext_vector_type(8))) short bfrag;
typedef __attribute__((ext_vector_type(4))) float ffrag;

__device__ __forceinline__ u16 f2b(float f) {
    union { float f; u32 u; } v; v.f = f;
    u32 r = v.u + 0x7fffu + ((v.u >> 16) & 1u);   // RNE
    return (u16)(r >> 16);
}

__device__ __forceinline__ float gelu_exact(float v) {
    return 0.5f * v * (1.0f + erff(v * 0.70710678118654752f));
}

// ---------------- mask pack: adj + diag -> bitmask [B*N][16] u64 -----------------
__global__ __launch_bounds__(256) void mask_pack(const int* __restrict__ adj,
                                                 u64* __restrict__ mb) {
    int idx = blockIdx.x * 256 + threadIdx.x;     // < 8*1024*16
    int w = idx & 15;
    int bi = idx >> 4;
    int i = bi & 1023;
    const int4* p = (const int4*)(adj + (size_t)bi * NN + w * 64);
    u64 m = 0;
#pragma unroll
    for (int q = 0; q < 16; ++q) {
        int4 v = p[q];
        if (v.x > 0) m |= 1ull << (q * 4 + 0);
        if (v.y > 0) m |= 1ull << (q * 4 + 1);
        if (v.z > 0) m |= 1ull << (q * 4 + 2);
        if (v.w > 0) m |= 1ull << (q * 4 + 3);
    }
    if (w == (i >> 6)) m |= 1ull << (i & 63);
    mb[idx] = m;
}

// ---------------- transpose + cvt: in fp32 [R][C] -> out bf16 [C][R] -------------
__global__ __launch_bounds__(256) void transpose_cvt(
    const float* __restrict__ in, u16* __restrict__ out,
    int R, int C, size_t inStr, size_t outStr)
{
    __shared__ float tile[32][33];
    int z = blockIdx.z;
    int r0 = blockIdx.y * 32, c0 = blockIdx.x * 32;
    int t = threadIdx.x;
    int tr = t >> 3, tc = (t & 7) * 4;
    float4 v = *(const float4*)(in + inStr * z + (size_t)(r0 + tr) * C + c0 + tc);
    tile[tr][tc + 0] = v.x; tile[tr][tc + 1] = v.y;
    tile[tr][tc + 2] = v.z; tile[tr][tc + 3] = v.w;
    __syncthreads();
    u32 w0 = (u32)f2b(tile[tc + 0][tr]) | ((u32)f2b(tile[tc + 1][tr]) << 16);
    u32 w1 = (u32)f2b(tile[tc + 2][tr]) | ((u32)f2b(tile[tc + 3][tr]) << 16);
    uint2 wv; wv.x = w0; wv.y = w1;
    *(uint2*)(out + outStr * z + (size_t)(c0 + tr) * R + r0 + tc) = wv;
}

// ---------------- score projection ----------------------------------------------
__global__ __launch_bounds__(256) void score_proj_kernel(
    const float* __restrict__ x, const float* __restrict__ w,
    float* __restrict__ si, float* __restrict__ sj)
{
    int wave = threadIdx.x >> 6;
    int lane = threadIdx.x & 63;
    int row = blockIdx.x * 4 + wave;
    const float4* xr = (const float4*)(x + (size_t)row * DD) + lane * 2;
    const float4* w1 = (const float4*)(w) + lane * 2;
    const float4* w2 = (const float4*)(w + DD) + lane * 2;
    float a = 0.f, b2 = 0.f;
#pragma unroll
    for (int c = 0; c < 2; ++c) {
        float4 xv = xr[c], wa = w1[c], wb = w2[c];
        a  += xv.x * wa.x + xv.y * wa.y + xv.z * wa.z + xv.w * wa.w;
        b2 += xv.x * wb.x + xv.y * wb.y + xv.z * wb.z + xv.w * wb.w;
    }
#pragma unroll
    for (int off = 32; off > 0; off >>= 1) {
        a  += __shfl_xor(a, off);
        b2 += __shfl_xor(b2, off);
    }
    if (lane == 0) { si[row] = a; sj[row] = b2; }
}

// ---------------- softmax -> P (bf16) --------------------------------------------
__global__ __launch_bounds__(256) void softmax_p(
    const float* __restrict__ si, const float* __restrict__ sj,
    const float* __restrict__ attn_b, const u64* __restrict__ mb,
    u16* __restrict__ P)
{
    __shared__ float sc[8][NN];       // 32 KB
    __shared__ float sinv[8];
    int b  = blockIdx.x >> 7;
    int i0 = (blockIdx.x & 127) * 8;
    int tid = threadIdx.x;
    int r = tid >> 5, l32 = tid & 31;
    int i = i0 + r;
    float bb = attn_b[0];
    float siv = si[b * NN + i];
    const float* sjb = sj + b * NN;
    const u64* mbr = mb + ((size_t)b * NN + i) * 16;

    float mx = -INFINITY;
#pragma unroll 4
    for (int q = 0; q < 32; ++q) {
        int j = q * 32 + l32;
        u64 w = mbr[q >> 1];
        int bit = ((q & 1) << 5) + l32;
        float s = siv + sjb[j] + bb;
        s = (s >= 0.f) ? s : 0.2f * s;
        s = ((w >> bit) & 1ull) ? s : -INFINITY;
        sc[r][j] = s;
        mx = fmaxf(mx, s);
    }
#pragma unroll
    for (int off = 16; off > 0; off >>= 1) mx = fmaxf(mx, __shfl_xor(mx, off, 32));
    float sum = 0.f;
#pragma unroll 4
    for (int q = 0; q < 32; ++q) {
        int j = q * 32 + l32;
        float p = __expf(sc[r][j] - mx);
        sc[r][j] = p;
        sum += p;
    }
#pragma unroll
    for (int off = 16; off > 0; off >>= 1) sum += __shfl_xor(sum, off, 32);
    if (l32 == 0) sinv[r] = 1.f / sum;
    __syncthreads();
    u16* Pb = P + ((size_t)b * NN + i0) * NN;
    for (int idx = tid; idx < 8 * NN; idx += 256) {
        int rr = idx >> 10, j = idx & 1023;
        Pb[(size_t)rr * NN + j] = f2b(sc[rr][j] * sinv[rr]);
    }
}

// ---------------- bf16 MFMA GEMM: C = epi(A@B^T) ---------------------------------
// A: [M][K] (fp32 or bf16), B: [N][K] bf16 (pre-transposed), 128x128 tile, BK=32.
// EPI: 0 = +res, fp32 out (agg) | 1 = +bias, GELU, bf16 out | 2 = +bias +res, fp32 out
template <typename AT, int EPI>
__global__ __launch_bounds__(256) void gemm_bf16(
    const AT* __restrict__ A, const u16* __restrict__ Bm,
    const float* __restrict__ bias, const float* __restrict__ res,
    void* __restrict__ Cout, int M, int K, int N,
    size_t aStr, size_t bStr, size_t cStr, size_t resStr)
{
    __shared__ __align__(16) u16 As[128][40];
    __shared__ __align__(16) u16 Bs[128][40];
    int z = blockIdx.z;
    int m0 = blockIdx.y * 128, n0 = blockIdx.x * 128;
    int tid = threadIdx.x;
    int srow = tid >> 1, skh = (tid & 1) * 16;
    const AT*  ag = A  + aStr * z + (size_t)(m0 + srow) * K + skh;
    const u16* bg = Bm + bStr * z + (size_t)(n0 + srow) * K + skh;

    int lane = tid & 63, wv = tid >> 6;
    int mw = (wv >> 1) * 64, nw = (wv & 1) * 64;
    int lr = lane & 15, lq = lane >> 4;

    ffrag acc[4][4];
#pragma unroll
    for (int i = 0; i < 4; ++i)
#pragma unroll
        for (int j = 0; j < 4; ++j) acc[i][j] = (ffrag){0.f, 0.f, 0.f, 0.f};

    for (int k0 = 0; k0 < K; k0 += 32) {
        uint4 aw0, aw1, bw0, bw1;
        if constexpr (sizeof(AT) == 4) {
            float4 f0 = *(const float4*)(ag + k0);
            float4 f1 = *(const float4*)(ag + k0 + 4);
            float4 f2 = *(const float4*)(ag + k0 + 8);
            float4 f3 = *(const float4*)(ag + k0 + 12);
            aw0.x = (u32)f2b(f0.x) | ((u32)f2b(f0.y) << 16);
            aw0.y = (u32)f2b(f0.z) | ((u32)f2b(f0.w) << 16);
            aw0.z = (u32)f2b(f1.x) | ((u32)f2b(f1.y) << 16);
            aw0.w = (u32)f2b(f1.z) | ((u32)f2b(f1.w) << 16);
            aw1.x = (u32)f2b(f2.x) | ((u32)f2b(f2.y) << 16);
            aw1.y = (u32)f2b(f2.z) | ((u32)f2b(f2.w) << 16);
            aw1.z = (u32)f2b(f3.x) | ((u32)f2b(f3.y) << 16);
            aw1.w = (u32)f2b(f3.z) | ((u32)f2b(f3.w) << 16);
        } else {
            aw0 = *(const uint4*)(ag + k0);
            aw1 = *(const uint4*)(ag + k0 + 8);
        }
        bw0 = *(const uint4*)(bg + k0);
        bw1 = *(const uint4*)(bg + k0 + 8);
        __syncthreads();
        *(uint4*)&As[srow][skh]     = aw0;
        *(uint4*)&As[srow][skh + 8] = aw1;
        *(uint4*)&Bs[srow][skh]     = bw0;
        *(uint4*)&Bs[srow][skh + 8] = bw1;
        __syncthreads();
        bfrag af[4], bf[4];
#pragma unroll
        for (int i = 0; i < 4; ++i) af[i] = *(const bfrag*)&As[mw + i * 16 + lr][lq * 8];
#pragma unroll
        for (int j = 0; j < 4; ++j) bf[j] = *(const bfrag*)&Bs[nw + j * 16 + lr][lq * 8];
#pragma unroll
        for (int i = 0; i < 4; ++i)
#pragma unroll
            for (int j = 0; j < 4; ++j)
                acc[i][j] = __builtin_amdgcn_mfma_f32_16x16x32_bf16(af[i], bf[j], acc[i][j], 0, 0, 0);
    }

    float* Cf  = (float*)Cout + cStr * z;
    u16*   Cb  = (u16*)Cout;
    const float* resb = res ? res + resStr * z : nullptr;
#pragma unroll
    for (int i = 0; i < 4; ++i) {
        int row = m0 + mw + i * 16 + lq * 4;
#pragma unroll
        for (int j = 0; j < 4; ++j) {
            int col = n0 + nw + j * 16 + lr;
            float bv = (EPI != 0) ? bias[col] : 0.f;
#pragma unroll
            for (int r = 0; r < 4; ++r) {
                float v = acc[i][j][r] + bv;
                size_t off = (size_t)(row + r) * N + col;
                if (EPI == 1) {
                    Cb[off] = f2b(gelu_exact(v));
                } else {
                    if (EPI == 0 || EPI == 2) v += resb[off];
                    Cf[off] = v;
                }
            }
        }
    }
}

// ---------------- layernorm over D=512, one row per block ------------------------
__global__ __launch_bounds__(256) void ln_kernel(
    const float* __restrict__ in, const float* __restrict__ g,
    const float* __restrict__ be, float* __restrict__ out)
{
    int row = blockIdx.x;
    int tid = threadIdx.x;
    const float2* rp = (const float2*)(in + (size_t)row * DD);
    float2 v = rp[tid];
    float s  = v.x + v.y;
    float ss = v.x * v.x + v.y * v.y;
#pragma unroll
    for (int off = 32; off > 0; off >>= 1) {
        s  += __shfl_xor(s, off);
        ss += __shfl_xor(ss, off);
    }
    __shared__ float sh[8];
    int wave = tid >> 6, lane = tid & 63;
    if (lane == 0) { sh[wave] = s; sh[4 + wave] = ss; }
    __syncthreads();
    float S  = sh[0] + sh[1] + sh[2] + sh[3];
    float SS = sh[4] + sh[5] + sh[6] + sh[7];
    float mean = S * (1.f / DD);
    float var  = SS * (1.f / DD) - mean * mean;
    var = fmaxf(var, 0.f);
    float rs = rsqrtf(var + 1e-5f);
    float2 gv = ((const float2*)g)[tid];
    float2 bv = ((const float2*)be)[tid];
    float2 o;
    o.x = (v.x - mean) * rs * gv.x + bv.x;
    o.y = (v.y - mean) * rs * gv.y + bv.y;
    ((float2*)(out + (size_t)row * DD))[tid] = o;
}

extern "C" void kernel_launch(void* const* d_in, const int* in_sizes, int n_in,
                              void* d_out, int out_size, void* d_ws, size_t ws_size,
                              hipStream_t stream) {
    const float* nf     = (const float*)d_in[0];
    const int*   adj    = (const int*)d_in[1];
    const float* attn_w = (const float*)d_in[2];
    const float* attn_b = (const float*)d_in[3];
    const float* W1     = (const float*)d_in[4];
    const float* b1     = (const float*)d_in[5];
    const float* W2     = (const float*)d_in[6];
    const float* b2     = (const float*)d_in[7];
    const float* g1     = (const float*)d_in[8];
    const float* be1    = (const float*)d_in[9];
    const float* g2     = (const float*)d_in[10];
    const float* be2    = (const float*)d_in[11];
    float* out = (float*)d_out;

    char* wsb = (char*)d_ws;
    float* x_cur   = (float*)(wsb);                    // 16 MB
    float* h       = (float*)(wsb + 16777216);         // 16 MB
    char*  scratch = wsb + 33554432;                   // 32 MB shared region
    u16*   P       = (u16*)scratch;                    //   P: [0,16MB)
    float* hres    = (float*)(scratch + 16777216);     //   hres: [16,32MB)
    u16*   mid     = (u16*)scratch;                    //   mid: [0,32MB) after ln1
    u16*   xT      = (u16*)(wsb + 67108864);           // 8 MB
    u16*   W1t     = (u16*)(wsb + 75497472);           // 6 MB
    u16*   W2t     = (u16*)(wsb + 81788928);           // 6 MB
    u64*   mask    = (u64*)(wsb + 88080384);           // 1 MB
    float* si      = (float*)(wsb + 89128960);         // 32 KB
    float* sj      = (float*)(wsb + 89161728);         // 32 KB

    // one-time prep (re-done every call; cheap)
    mask_pack<<<512, 256, 0, stream>>>(adj, mask);
    transpose_cvt<<<dim3(64, 16, 3), 256, 0, stream>>>(W1, W1t, 512, 2048,
                                                       (size_t)512 * 2048, (size_t)512 * 2048);
    transpose_cvt<<<dim3(16, 64, 3), 256, 0, stream>>>(W2, W2t, 2048, 512,
                                                       (size_t)2048 * 512, (size_t)2048 * 512);

    for (int l = 0; l < 3; ++l) {
        const float* xin = (l == 0) ? nf : x_cur;
        score_proj_kernel<<<2048, 256, 0, stream>>>(xin, attn_w + (size_t)l * 1024, si, sj);
        transpose_cvt<<<dim3(16, 32, 8), 256, 0, stream>>>(xin, xT, 1024, 512,
                                                           (size_t)NN * DD, (size_t)NN * DD);
        softmax_p<<<1024, 256, 0, stream>>>(si, sj, attn_b + l, mask, P);
        // agg: hres[b] = P[b] @ x[b] + x[b]
        gemm_bf16<u16, 0><<<dim3(4, 8, 8), 256, 0, stream>>>(
            P, xT, nullptr, xin, hres, 1024, 1024, 512,
            (size_t)NN * NN, (size_t)DD * NN, (size_t)NN * DD, (size_t)NN * DD);
        ln_kernel<<<8192, 256, 0, stream>>>(hres, g1 + (size_t)l * 512, be1 + (size_t)l * 512, h);
        // FFN1: mid = gelu(h @ W1 + b1)  (bf16 out)
        gemm_bf16<float, 1><<<dim3(16, 64, 1), 256, 0, stream>>>(
            h, W1t + (size_t)l * 1048576, b1 + (size_t)l * 2048, nullptr, mid,
            8192, 512, 2048, 0, 0, 0, 0);
        // FFN2: x_cur = mid @ W2 + b2 + h
        gemm_bf16<u16, 2><<<dim3(4, 64, 1), 256, 0, stream>>>(
            mid, W2t + (size_t)l * 1048576, b2 + (size_t)l * 512, h, x_cur,
            8192, 2048, 512, 0, 0, 0, 0);
        float* lnout = (l == 2) ? out : x_cur;
        ln_kernel<<<8192, 256, 0, stream>>>(x_cur, g2 + (size_t)l * 512, be2 + (size_t)l * 512, lnout);
    }
}

// Round 3
// 623.845 us; speedup vs baseline: 5.4296x; 1.0916x over previous
//
#include <hip/hip_runtime.h>
#include <math.h>

#define NB 8
#define NN 1024
#define DD 512

typedef unsigned short u16;
typedef unsigned int u32;
typedef unsigned long long u64;
typedef __attribute__((ext_vector_type(8))) short bfrag;
typedef __attribute__((ext_vector_type(4))) float ffrag;

__device__ __forceinline__ u16 f2b(float f) {
    union { float f; u32 u; } v; v.f = f;
    u32 r = v.u + 0x7fffu + ((v.u >> 16) & 1u);   // RNE
    return (u16)(r >> 16);
}
__device__ __forceinline__ float b2f(u16 b) {
    union { u32 u; float f; } v; v.u = ((u32)b) << 16;
    return v.f;
}

__device__ __forceinline__ float gelu_exact(float v) {
    return 0.5f * v * (1.0f + erff(v * 0.70710678118654752f));
}

// async global->LDS, 16B per lane; lds base must be wave-uniform
__device__ __forceinline__ void gload_lds16(const void* g, void* l) {
    __builtin_amdgcn_global_load_lds(
        (const __attribute__((address_space(1))) void*)g,
        (__attribute__((address_space(3))) void*)l, 16, 0, 0);
}

// ---------------- mask pack: adj + diag -> bitmask [B*N][16] u64 -----------------
__global__ __launch_bounds__(256) void mask_pack(const int* __restrict__ adj,
                                                 u64* __restrict__ mb) {
    int idx = blockIdx.x * 256 + threadIdx.x;     // < 8*1024*16
    int w = idx & 15;
    int bi = idx >> 4;
    int i = bi & 1023;
    const int4* p = (const int4*)(adj + (size_t)bi * NN + w * 64);
    u64 m = 0;
#pragma unroll
    for (int q = 0; q < 16; ++q) {
        int4 v = p[q];
        if (v.x > 0) m |= 1ull << (q * 4 + 0);
        if (v.y > 0) m |= 1ull << (q * 4 + 1);
        if (v.z > 0) m |= 1ull << (q * 4 + 2);
        if (v.w > 0) m |= 1ull << (q * 4 + 3);
    }
    if (w == (i >> 6)) m |= 1ull << (i & 63);
    mb[idx] = m;
}

// ---------------- transpose + cvt: in fp32 [R][C] -> out bf16 [C][R] -------------
__global__ __launch_bounds__(256) void transpose_cvt(
    const float* __restrict__ in, u16* __restrict__ out,
    int R, int C, size_t inStr, size_t outStr)
{
    __shared__ float tile[32][33];
    int z = blockIdx.z;
    int r0 = blockIdx.y * 32, c0 = blockIdx.x * 32;
    int t = threadIdx.x;
    int tr = t >> 3, tc = (t & 7) * 4;
    float4 v = *(const float4*)(in + inStr * z + (size_t)(r0 + tr) * C + c0 + tc);
    tile[tr][tc + 0] = v.x; tile[tr][tc + 1] = v.y;
    tile[tr][tc + 2] = v.z; tile[tr][tc + 3] = v.w;
    __syncthreads();
    u32 w0 = (u32)f2b(tile[tc + 0][tr]) | ((u32)f2b(tile[tc + 1][tr]) << 16);
    u32 w1 = (u32)f2b(tile[tc + 2][tr]) | ((u32)f2b(tile[tc + 3][tr]) << 16);
    uint2 wv; wv.x = w0; wv.y = w1;
    *(uint2*)(out + outStr * z + (size_t)(c0 + tr) * R + r0 + tc) = wv;
}

// ---------------- score projection ----------------------------------------------
__global__ __launch_bounds__(256) void score_proj_kernel(
    const float* __restrict__ x, const float* __restrict__ w,
    float* __restrict__ si, float* __restrict__ sj)
{
    int wave = threadIdx.x >> 6;
    int lane = threadIdx.x & 63;
    int row = blockIdx.x * 4 + wave;
    const float4* xr = (const float4*)(x + (size_t)row * DD) + lane * 2;
    const float4* w1 = (const float4*)(w) + lane * 2;
    const float4* w2 = (const float4*)(w + DD) + lane * 2;
    float a = 0.f, b2 = 0.f;
#pragma unroll
    for (int c = 0; c < 2; ++c) {
        float4 xv = xr[c], wa = w1[c], wb = w2[c];
        a  += xv.x * wa.x + xv.y * wa.y + xv.z * wa.z + xv.w * wa.w;
        b2 += xv.x * wb.x + xv.y * wb.y + xv.z * wb.z + xv.w * wb.w;
    }
#pragma unroll
    for (int off = 32; off > 0; off >>= 1) {
        a  += __shfl_xor(a, off);
        b2 += __shfl_xor(b2, off);
    }
    if (lane == 0) { si[row] = a; sj[row] = b2; }
}

// ---------------- softmax -> P (bf16) --------------------------------------------
__global__ __launch_bounds__(256) void softmax_p(
    const float* __restrict__ si, const float* __restrict__ sj,
    const float* __restrict__ attn_b, const u64* __restrict__ mb,
    u16* __restrict__ P)
{
    __shared__ float sc[8][NN];       // 32 KB
    __shared__ float sinv[8];
    int b  = blockIdx.x >> 7;
    int i0 = (blockIdx.x & 127) * 8;
    int tid = threadIdx.x;
    int r = tid >> 5, l32 = tid & 31;
    int i = i0 + r;
    float bb = attn_b[0];
    float siv = si[b * NN + i];
    const float* sjb = sj + b * NN;
    const u64* mbr = mb + ((size_t)b * NN + i) * 16;

    float mx = -INFINITY;
#pragma unroll 4
    for (int q = 0; q < 32; ++q) {
        int j = q * 32 + l32;
        u64 w = mbr[q >> 1];
        int bit = ((q & 1) << 5) + l32;
        float s = siv + sjb[j] + bb;
        s = (s >= 0.f) ? s : 0.2f * s;
        s = ((w >> bit) & 1ull) ? s : -INFINITY;
        sc[r][j] = s;
        mx = fmaxf(mx, s);
    }
#pragma unroll
    for (int off = 16; off > 0; off >>= 1) mx = fmaxf(mx, __shfl_xor(mx, off, 32));
    float sum = 0.f;
#pragma unroll 4
    for (int q = 0; q < 32; ++q) {
        int j = q * 32 + l32;
        float p = __expf(sc[r][j] - mx);
        sc[r][j] = p;
        sum += p;
    }
#pragma unroll
    for (int off = 16; off > 0; off >>= 1) sum += __shfl_xor(sum, off, 32);
    if (l32 == 0) sinv[r] = 1.f / sum;
    __syncthreads();
    u16* Pb = P + ((size_t)b * NN + i0) * NN;
    for (int idx = tid; idx < 8 * NN; idx += 256) {
        int rr = idx >> 10, j = idx & 1023;
        Pb[(size_t)rr * NN + j] = f2b(sc[rr][j] * sinv[rr]);
    }
}

// ---------------- bf16 MFMA GEMM, global_load_lds staging ------------------------
// A: [M rows][lda] bf16, B: [N rows][ldb] bf16 (pre-transposed). 128x128 tile, BK=32.
// EPI: 0 = +res(fp32), fp32 out | 1 = +bias, GELU, bf16 out | 2 = +bias +res(bf16), fp32 out
template <int EPI>
__global__ __launch_bounds__(256) void gemm_bf16(
    const u16* __restrict__ A, const u16* __restrict__ Bm,
    const float* __restrict__ bias, const void* __restrict__ res,
    void* __restrict__ Cout, int K, int N, int lda, int ldb,
    size_t aStr, size_t bStr, size_t cStr, size_t resStr)
{
    __shared__ __align__(16) u16 As[128 * 32];
    __shared__ __align__(16) u16 Bs[128 * 32];
    int z = blockIdx.z;
    int m0 = blockIdx.y * 128, n0 = blockIdx.x * 128;
    int tid = threadIdx.x;
    int lane = tid & 63, wv = tid >> 6;

    // staging: chunk q (16B) -> row q>>2, colchunk q&3; LDS offset q*8 elems
    int q0 = tid;            // chunks 0..255 (issue 0)
    int q1 = tid + 256;      // chunks 256..511 (issue 1)
    const u16* agl = A + aStr * z + (size_t)(m0 + (q0 >> 2)) * lda + (q0 & 3) * 8;
    const u16* agh = A + aStr * z + (size_t)(m0 + (q1 >> 2)) * lda + (q1 & 3) * 8;
    const u16* bgl = Bm + bStr * z + (size_t)(n0 + (q0 >> 2)) * ldb + (q0 & 3) * 8;
    const u16* bgh = Bm + bStr * z + (size_t)(n0 + (q1 >> 2)) * ldb + (q1 & 3) * 8;
    u16* lA0 = As + wv * 512;          // wave-uniform bases
    u16* lA1 = As + 2048 + wv * 512;
    u16* lB0 = Bs + wv * 512;
    u16* lB1 = Bs + 2048 + wv * 512;

    int mw = (wv >> 1) * 64, nw = (wv & 1) * 64;
    int lr = lane & 15, lq = lane >> 4;

    ffrag acc[4][4];
#pragma unroll
    for (int i = 0; i < 4; ++i)
#pragma unroll
        for (int j = 0; j < 4; ++j) acc[i][j] = (ffrag){0.f, 0.f, 0.f, 0.f};

    for (int k0 = 0; k0 < K; k0 += 32) {
        __syncthreads();               // previous iter's frag reads done
        gload_lds16(agl + k0, lA0);
        gload_lds16(agh + k0, lA1);
        gload_lds16(bgl + k0, lB0);
        gload_lds16(bgh + k0, lB1);
        __syncthreads();               // vmcnt(0) drain: data arrived
        bfrag af[4], bf[4];
#pragma unroll
        for (int i = 0; i < 4; ++i) af[i] = *(const bfrag*)&As[(mw + i * 16 + lr) * 32 + lq * 8];
#pragma unroll
        for (int j = 0; j < 4; ++j) bf[j] = *(const bfrag*)&Bs[(nw + j * 16 + lr) * 32 + lq * 8];
#pragma unroll
        for (int i = 0; i < 4; ++i)
#pragma unroll
            for (int j = 0; j < 4; ++j)
                acc[i][j] = __builtin_amdgcn_mfma_f32_16x16x32_bf16(af[i], bf[j], acc[i][j], 0, 0, 0);
    }

    float* Cf = (float*)Cout + cStr * z;
    u16*   Cb = (u16*)Cout + cStr * z;
    const float* resf = (const float*)res;
    const u16*   resb = (const u16*)res;
#pragma unroll
    for (int i = 0; i < 4; ++i) {
        int row = m0 + mw + i * 16 + lq * 4;
#pragma unroll
        for (int j = 0; j < 4; ++j) {
            int col = n0 + nw + j * 16 + lr;
            float bv = (EPI != 0) ? bias[col] : 0.f;
#pragma unroll
            for (int r = 0; r < 4; ++r) {
                float v = acc[i][j][r] + bv;
                size_t off = (size_t)(row + r) * N + col;
                if (EPI == 1) {
                    Cb[off] = f2b(gelu_exact(v));
                } else if (EPI == 0) {
                    Cf[off] = v + resf[resStr * z + off];
                } else {
                    Cf[off] = v + b2f(resb[off]);
                }
            }
        }
    }
}

// ---------------- layernorm over D=512, one row per block ------------------------
// BF=true: write bf16, else fp32
template <bool BF>
__global__ __launch_bounds__(256) void ln_kernel(
    const float* __restrict__ in, const float* __restrict__ g,
    const float* __restrict__ be, void* __restrict__ out)
{
    int row = blockIdx.x;
    int tid = threadIdx.x;
    const float2* rp = (const float2*)(in + (size_t)row * DD);
    float2 v = rp[tid];
    float s  = v.x + v.y;
    float ss = v.x * v.x + v.y * v.y;
#pragma unroll
    for (int off = 32; off > 0; off >>= 1) {
        s  += __shfl_xor(s, off);
        ss += __shfl_xor(ss, off);
    }
    __shared__ float sh[8];
    int wave = tid >> 6, lane = tid & 63;
    if (lane == 0) { sh[wave] = s; sh[4 + wave] = ss; }
    __syncthreads();
    float S  = sh[0] + sh[1] + sh[2] + sh[3];
    float SS = sh[4] + sh[5] + sh[6] + sh[7];
    float mean = S * (1.f / DD);
    float var  = SS * (1.f / DD) - mean * mean;
    var = fmaxf(var, 0.f);
    float rs = rsqrtf(var + 1e-5f);
    float2 gv = ((const float2*)g)[tid];
    float2 bv = ((const float2*)be)[tid];
    float ox = (v.x - mean) * rs * gv.x + bv.x;
    float oy = (v.y - mean) * rs * gv.y + bv.y;
    if (BF) {
        u32 w = (u32)f2b(ox) | ((u32)f2b(oy) << 16);
        ((u32*)out)[(size_t)row * (DD / 2) + tid] = w;
    } else {
        float2 o; o.x = ox; o.y = oy;
        ((float2*)out)[(size_t)row * (DD / 2) + tid] = o;
    }
}

extern "C" void kernel_launch(void* const* d_in, const int* in_sizes, int n_in,
                              void* d_out, int out_size, void* d_ws, size_t ws_size,
                              hipStream_t stream) {
    const float* nf     = (const float*)d_in[0];
    const int*   adj    = (const int*)d_in[1];
    const float* attn_w = (const float*)d_in[2];
    const float* attn_b = (const float*)d_in[3];
    const float* W1     = (const float*)d_in[4];
    const float* b1     = (const float*)d_in[5];
    const float* W2     = (const float*)d_in[6];
    const float* b2     = (const float*)d_in[7];
    const float* g1     = (const float*)d_in[8];
    const float* be1    = (const float*)d_in[9];
    const float* g2     = (const float*)d_in[10];
    const float* be2    = (const float*)d_in[11];
    float* out = (float*)d_out;

    char* wsb = (char*)d_ws;
    float* x_cur = (float*)(wsb);                      // 16 MB [0,16M)
    u16*   h_bf  = (u16*)(wsb + 16777216);             //  8 MB [16,24M)
    char*  scr   = wsb + 25165824;                     // 32 MB [24,56M)
    u16*   P     = (u16*)scr;                          //   [24,40M)
    float* hres  = (float*)(scr + 16777216);           //   [40,56M)
    u16*   mid   = (u16*)scr;                          //   [24,56M) after ln1 (P,hres dead)
    u16*   xT    = (u16*)(wsb + 58720256);             //  8 MB [56,64M)
    u16*   W1t   = (u16*)(wsb + 67108864);             //  6 MB [64,70M)
    u16*   W2t   = (u16*)(wsb + 73400320);             //  6 MB [70,76M)
    u64*   mask  = (u64*)(wsb + 79691776);             //  1 MB [76,77M)
    float* si    = (float*)(wsb + 80740352);           // 32 KB
    float* sj    = (float*)(wsb + 80773120);           // 32 KB

    // prep (re-done every call; cheap)
    mask_pack<<<512, 256, 0, stream>>>(adj, mask);
    transpose_cvt<<<dim3(64, 16, 3), 256, 0, stream>>>(W1, W1t, 512, 2048,
                                                       (size_t)512 * 2048, (size_t)512 * 2048);
    transpose_cvt<<<dim3(16, 64, 3), 256, 0, stream>>>(W2, W2t, 2048, 512,
                                                       (size_t)2048 * 512, (size_t)2048 * 512);

    for (int l = 0; l < 3; ++l) {
        const float* xin = (l == 0) ? nf : x_cur;
        score_proj_kernel<<<2048, 256, 0, stream>>>(xin, attn_w + (size_t)l * 1024, si, sj);
        transpose_cvt<<<dim3(16, 32, 8), 256, 0, stream>>>(xin, xT, 1024, 512,
                                                           (size_t)NN * DD, (size_t)NN * DD);
        softmax_p<<<1024, 256, 0, stream>>>(si, sj, attn_b + l, mask, P);
        // agg: hres[b] = P[b] @ x[b]^T + x[b]
        gemm_bf16<0><<<dim3(4, 8, 8), 256, 0, stream>>>(
            P, xT, nullptr, xin, hres, 1024, 512, 1024, 1024,
            (size_t)NN * NN, (size_t)DD * NN, (size_t)NN * DD, (size_t)NN * DD);
        // ln1 -> bf16 h
        ln_kernel<true><<<8192, 256, 0, stream>>>(hres, g1 + (size_t)l * 512, be1 + (size_t)l * 512, h_bf);
        // FFN1: mid = gelu(h @ W1 + b1)  (bf16 out)
        gemm_bf16<1><<<dim3(16, 64, 1), 256, 0, stream>>>(
            h_bf, W1t + (size_t)l * 1048576, b1 + (size_t)l * 2048, nullptr, mid,
            512, 2048, 512, 512, 0, 0, 0, 0);
        // FFN2: x_cur = mid @ W2 + b2 + h
        gemm_bf16<2><<<dim3(4, 64, 1), 256, 0, stream>>>(
            mid, W2t + (size_t)l * 1048576, b2 + (size_t)l * 512, h_bf, x_cur,
            2048, 512, 2048, 2048, 0, 0, 0, 0);
        void* lnout = (l == 2) ? (void*)out : (void*)x_cur;
        ln_kernel<false><<<8192, 256, 0, stream>>>(x_cur, g2 + (size_t)l * 512, be2 + (size_t)l * 512, lnout);
    }
}

// Round 4
// 506.996 us; speedup vs baseline: 6.6809x; 1.2305x over previous
//
#include <hip/hip_runtime.h>
#include <math.h>

#define NB 8
#define NN 1024
#define DD 512

typedef unsigned short u16;
typedef unsigned int u32;
typedef unsigned long long u64;
typedef __attribute__((ext_vector_type(8))) short bfrag;
typedef __attribute__((ext_vector_type(4))) float ffrag;

__device__ __forceinline__ u16 f2b(float f) {
    union { float f; u32 u; } v; v.f = f;
    u32 r = v.u + 0x7fffu + ((v.u >> 16) & 1u);   // RNE
    return (u16)(r >> 16);
}
__device__ __forceinline__ float b2f(u16 b) {
    union { u32 u; float f; } v; v.u = ((u32)b) << 16;
    return v.f;
}

// A&S 7.1.26 erf: |err| <= 1.5e-7, ~14 VALU (vs branchy ocml erff)
__device__ __forceinline__ float gelu_cheap(float v) {
    float s = v * 0.70710678118654752f;
    float a = fabsf(s);
    float t = 1.0f / (1.0f + 0.3275911f * a);
    float p = ((((1.061405429f * t - 1.453152027f) * t + 1.421413741f) * t
                - 0.284496736f) * t + 0.254829592f) * t;
    float erfa = 1.0f - p * __expf(-a * a);
    float erfs = copysignf(erfa, s);
    return 0.5f * v * (1.0f + erfs);
}

// async global->LDS, 16B per lane; lds base must be wave-uniform
__device__ __forceinline__ void gload_lds16(const void* g, void* l) {
    __builtin_amdgcn_global_load_lds(
        (const __attribute__((address_space(1))) void*)g,
        (__attribute__((address_space(3))) void*)l, 16, 0, 0);
}

// ---------------- mask pack: adj + diag -> bitmask [B*N][16] u64 -----------------
__global__ __launch_bounds__(256) void mask_pack(const int* __restrict__ adj,
                                                 u64* __restrict__ mb) {
    int idx = blockIdx.x * 256 + threadIdx.x;     // < 8*1024*16
    int w = idx & 15;
    int bi = idx >> 4;
    int i = bi & 1023;
    const int4* p = (const int4*)(adj + (size_t)bi * NN + w * 64);
    u64 m = 0;
#pragma unroll
    for (int q = 0; q < 16; ++q) {
        int4 v = p[q];
        if (v.x > 0) m |= 1ull << (q * 4 + 0);
        if (v.y > 0) m |= 1ull << (q * 4 + 1);
        if (v.z > 0) m |= 1ull << (q * 4 + 2);
        if (v.w > 0) m |= 1ull << (q * 4 + 3);
    }
    if (w == (i >> 6)) m |= 1ull << (i & 63);
    mb[idx] = m;
}

// ---------------- transpose + cvt: in fp32 [R][C] -> out bf16 [C][R] -------------
__global__ __launch_bounds__(256) void transpose_cvt(
    const float* __restrict__ in, u16* __restrict__ out,
    int R, int C, size_t inStr, size_t outStr)
{
    __shared__ float tile[32][33];
    int z = blockIdx.z;
    int r0 = blockIdx.y * 32, c0 = blockIdx.x * 32;
    int t = threadIdx.x;
    int tr = t >> 3, tc = (t & 7) * 4;
    float4 v = *(const float4*)(in + inStr * z + (size_t)(r0 + tr) * C + c0 + tc);
    tile[tr][tc + 0] = v.x; tile[tr][tc + 1] = v.y;
    tile[tr][tc + 2] = v.z; tile[tr][tc + 3] = v.w;
    __syncthreads();
    u32 w0 = (u32)f2b(tile[tc + 0][tr]) | ((u32)f2b(tile[tc + 1][tr]) << 16);
    u32 w1 = (u32)f2b(tile[tc + 2][tr]) | ((u32)f2b(tile[tc + 3][tr]) << 16);
    uint2 wv; wv.x = w0; wv.y = w1;
    *(uint2*)(out + outStr * z + (size_t)(c0 + tr) * R + r0 + tc) = wv;
}

// ---------------- score projection ----------------------------------------------
__global__ __launch_bounds__(256) void score_proj_kernel(
    const float* __restrict__ x, const float* __restrict__ w,
    float* __restrict__ si, float* __restrict__ sj)
{
    int wave = threadIdx.x >> 6;
    int lane = threadIdx.x & 63;
    int row = blockIdx.x * 4 + wave;
    const float4* xr = (const float4*)(x + (size_t)row * DD) + lane * 2;
    const float4* w1 = (const float4*)(w) + lane * 2;
    const float4* w2 = (const float4*)(w + DD) + lane * 2;
    float a = 0.f, b2 = 0.f;
#pragma unroll
    for (int c = 0; c < 2; ++c) {
        float4 xv = xr[c], wa = w1[c], wb = w2[c];
        a  += xv.x * wa.x + xv.y * wa.y + xv.z * wa.z + xv.w * wa.w;
        b2 += xv.x * wb.x + xv.y * wb.y + xv.z * wb.z + xv.w * wb.w;
    }
#pragma unroll
    for (int off = 32; off > 0; off >>= 1) {
        a  += __shfl_xor(a, off);
        b2 += __shfl_xor(b2, off);
    }
    if (lane == 0) { si[row] = a; sj[row] = b2; }
}

// ---------------- softmax -> P (bf16) --------------------------------------------
__global__ __launch_bounds__(256) void softmax_p(
    const float* __restrict__ si, const float* __restrict__ sj,
    const float* __restrict__ attn_b, const u64* __restrict__ mb,
    u16* __restrict__ P)
{
    __shared__ float sc[8][NN];       // 32 KB
    __shared__ float sinv[8];
    int b  = blockIdx.x >> 7;
    int i0 = (blockIdx.x & 127) * 8;
    int tid = threadIdx.x;
    int r = tid >> 5, l32 = tid & 31;
    int i = i0 + r;
    float bb = attn_b[0];
    float siv = si[b * NN + i];
    const float* sjb = sj + b * NN;
    const u64* mbr = mb + ((size_t)b * NN + i) * 16;

    float mx = -INFINITY;
#pragma unroll 4
    for (int q = 0; q < 32; ++q) {
        int j = q * 32 + l32;
        u64 w = mbr[q >> 1];
        int bit = ((q & 1) << 5) + l32;
        float s = siv + sjb[j] + bb;
        s = (s >= 0.f) ? s : 0.2f * s;
        s = ((w >> bit) & 1ull) ? s : -INFINITY;
        sc[r][j] = s;
        mx = fmaxf(mx, s);
    }
#pragma unroll
    for (int off = 16; off > 0; off >>= 1) mx = fmaxf(mx, __shfl_xor(mx, off, 32));
    float sum = 0.f;
#pragma unroll 4
    for (int q = 0; q < 32; ++q) {
        int j = q * 32 + l32;
        float p = __expf(sc[r][j] - mx);
        sc[r][j] = p;
        sum += p;
    }
#pragma unroll
    for (int off = 16; off > 0; off >>= 1) sum += __shfl_xor(sum, off, 32);
    if (l32 == 0) sinv[r] = 1.f / sum;
    __syncthreads();
    u16* Pb = P + ((size_t)b * NN + i0) * NN;
    for (int idx = tid; idx < 8 * NN; idx += 256) {
        int rr = idx >> 10, j = idx & 1023;
        Pb[(size_t)rr * NN + j] = f2b(sc[rr][j] * sinv[rr]);
    }
}

// ======================= bf16 MFMA GEMMs, BK=64, XOR-swizzled LDS ================
// LDS layout: tile[row][c] holds global chunk (c ^ (row&7)); frag reads hit all
// 32 banks (2-way max). Swizzle folded into the GLOBAL address at staging time
// (global_load_lds cannot scatter in LDS).
// EPI: 0 = +res(fp32), fp32 out | 1 = +bias, gelu, bf16 out | 2 = +bias +res(bf16), fp32 out

template <int EPI>
__device__ __forceinline__ void gemm_epilogue(
    ffrag* acc /*[ni*4 flattened as acc[i*4+j] style*/, int dummy);

// ---- 128x128 tile (FFN1: 1024 blocks = 4/CU) ----
template <int EPI>
__global__ __launch_bounds__(256) void gemm128(
    const u16* __restrict__ A, const u16* __restrict__ Bm,
    const float* __restrict__ bias, const void* __restrict__ res,
    void* __restrict__ Cout, int K, int N, int lda, int ldb,
    size_t aStr, size_t bStr, size_t cStr, size_t resStr)
{
    __shared__ __align__(16) u16 As[128 * 64];   // 16 KB
    __shared__ __align__(16) u16 Bs[128 * 64];   // 16 KB
    int z = blockIdx.z;
    int m0 = blockIdx.y * 128, n0 = blockIdx.x * 128;
    int tid = threadIdx.x;
    int lane = tid & 63, wv = tid >> 6;

    // staging: 1024 chunks (16B) per tile, 4 issues/thread
    const u16* ag[4]; const u16* bg[4];
    u16* lA[4]; u16* lB[4];
#pragma unroll
    for (int i = 0; i < 4; ++i) {
        int q = i * 256 + tid;
        int row = q >> 3, c = q & 7;
        int gc = c ^ (row & 7);
        ag[i] = A  + aStr * z + (size_t)(m0 + row) * lda + gc * 8;
        bg[i] = Bm + bStr * z + (size_t)(n0 + row) * ldb + gc * 8;
        lA[i] = As + i * 2048 + wv * 512;
        lB[i] = Bs + i * 2048 + wv * 512;
    }

    int mw = (wv >> 1) * 64, nw = (wv & 1) * 64;
    int lr = lane & 15, lq = lane >> 4;
    int sw = lr & 7;

    ffrag acc[4][4];
#pragma unroll
    for (int i = 0; i < 4; ++i)
#pragma unroll
        for (int j = 0; j < 4; ++j) acc[i][j] = (ffrag){0.f, 0.f, 0.f, 0.f};

    for (int k0 = 0; k0 < K; k0 += 64) {
        __syncthreads();
#pragma unroll
        for (int i = 0; i < 4; ++i) gload_lds16(ag[i] + k0, lA[i]);
#pragma unroll
        for (int i = 0; i < 4; ++i) gload_lds16(bg[i] + k0, lB[i]);
        __syncthreads();
#pragma unroll
        for (int h = 0; h < 2; ++h) {
            bfrag af[4], bf[4];
#pragma unroll
            for (int i = 0; i < 4; ++i)
                af[i] = *(const bfrag*)&As[(mw + i * 16 + lr) * 64 + (((h * 4 + lq) ^ sw)) * 8];
#pragma unroll
            for (int j = 0; j < 4; ++j)
                bf[j] = *(const bfrag*)&Bs[(nw + j * 16 + lr) * 64 + (((h * 4 + lq) ^ sw)) * 8];
#pragma unroll
            for (int i = 0; i < 4; ++i)
#pragma unroll
                for (int j = 0; j < 4; ++j)
                    acc[i][j] = __builtin_amdgcn_mfma_f32_16x16x32_bf16(af[i], bf[j], acc[i][j], 0, 0, 0);
        }
    }

    float* Cf = (float*)Cout + cStr * z;
    u16*   Cb = (u16*)Cout + cStr * z;
    const float* resf = (const float*)res;
    const u16*   resb = (const u16*)res;
#pragma unroll
    for (int i = 0; i < 4; ++i) {
        int row = m0 + mw + i * 16 + lq * 4;
#pragma unroll
        for (int j = 0; j < 4; ++j) {
            int col = n0 + nw + j * 16 + lr;
            float bv = (EPI != 0) ? bias[col] : 0.f;
#pragma unroll
            for (int r = 0; r < 4; ++r) {
                float v = acc[i][j][r] + bv;
                size_t off = (size_t)(row + r) * N + col;
                if (EPI == 1) {
                    Cb[off] = f2b(gelu_cheap(v));
                } else if (EPI == 0) {
                    Cf[off] = v + resf[resStr * z + off];
                } else {
                    Cf[off] = v + b2f(resb[off]);
                }
            }
        }
    }
}

// ---- 64x128 tile (agg / FFN2: 512 blocks = 2/CU) ----
template <int EPI>
__global__ __launch_bounds__(256) void gemm64(
    const u16* __restrict__ A, const u16* __restrict__ Bm,
    const float* __restrict__ bias, const void* __restrict__ res,
    void* __restrict__ Cout, int K, int N, int lda, int ldb,
    size_t aStr, size_t bStr, size_t cStr, size_t resStr)
{
    __shared__ __align__(16) u16 As[64 * 64];    //  8 KB
    __shared__ __align__(16) u16 Bs[128 * 64];   // 16 KB
    int z = blockIdx.z;
    int m0 = blockIdx.y * 64, n0 = blockIdx.x * 128;
    int tid = threadIdx.x;
    int lane = tid & 63, wv = tid >> 6;

    const u16* ag[2]; const u16* bg[4];
    u16* lA[2]; u16* lB[4];
#pragma unroll
    for (int i = 0; i < 2; ++i) {
        int q = i * 256 + tid;
        int row = q >> 3, c = q & 7;
        int gc = c ^ (row & 7);
        ag[i] = A + aStr * z + (size_t)(m0 + row) * lda + gc * 8;
        lA[i] = As + i * 2048 + wv * 512;
    }
#pragma unroll
    for (int i = 0; i < 4; ++i) {
        int q = i * 256 + tid;
        int row = q >> 3, c = q & 7;
        int gc = c ^ (row & 7);
        bg[i] = Bm + bStr * z + (size_t)(n0 + row) * ldb + gc * 8;
        lB[i] = Bs + i * 2048 + wv * 512;
    }

    int mw = (wv >> 1) * 32, nw = (wv & 1) * 64;   // wave covers 32(M) x 64(N)
    int lr = lane & 15, lq = lane >> 4;
    int sw = lr & 7;

    ffrag acc[2][4];
#pragma unroll
    for (int i = 0; i < 2; ++i)
#pragma unroll
        for (int j = 0; j < 4; ++j) acc[i][j] = (ffrag){0.f, 0.f, 0.f, 0.f};

    for (int k0 = 0; k0 < K; k0 += 64) {
        __syncthreads();
#pragma unroll
        for (int i = 0; i < 2; ++i) gload_lds16(ag[i] + k0, lA[i]);
#pragma unroll
        for (int i = 0; i < 4; ++i) gload_lds16(bg[i] + k0, lB[i]);
        __syncthreads();
#pragma unroll
        for (int h = 0; h < 2; ++h) {
            bfrag af[2], bf[4];
#pragma unroll
            for (int i = 0; i < 2; ++i)
                af[i] = *(const bfrag*)&As[(mw + i * 16 + lr) * 64 + (((h * 4 + lq) ^ sw)) * 8];
#pragma unroll
            for (int j = 0; j < 4; ++j)
                bf[j] = *(const bfrag*)&Bs[(nw + j * 16 + lr) * 64 + (((h * 4 + lq) ^ sw)) * 8];
#pragma unroll
            for (int i = 0; i < 2; ++i)
#pragma unroll
                for (int j = 0; j < 4; ++j)
                    acc[i][j] = __builtin_amdgcn_mfma_f32_16x16x32_bf16(af[i], bf[j], acc[i][j], 0, 0, 0);
        }
    }

    float* Cf = (float*)Cout + cStr * z;
    u16*   Cb = (u16*)Cout + cStr * z;
    const float* resf = (const float*)res;
    const u16*   resb = (const u16*)res;
#pragma unroll
    for (int i = 0; i < 2; ++i) {
        int row = m0 + mw + i * 16 + lq * 4;
#pragma unroll
        for (int j = 0; j < 4; ++j) {
            int col = n0 + nw + j * 16 + lr;
            float bv = (EPI != 0) ? bias[col] : 0.f;
#pragma unroll
            for (int r = 0; r < 4; ++r) {
                float v = acc[i][j][r] + bv;
                size_t off = (size_t)(row + r) * N + col;
                if (EPI == 1) {
                    Cb[off] = f2b(gelu_cheap(v));
                } else if (EPI == 0) {
                    Cf[off] = v + resf[resStr * z + off];
                } else {
                    Cf[off] = v + b2f(resb[off]);
                }
            }
        }
    }
}

// ---------------- layernorm over D=512, one row per block ------------------------
// BF=true: write bf16, else fp32
template <bool BF>
__global__ __launch_bounds__(256) void ln_kernel(
    const float* __restrict__ in, const float* __restrict__ g,
    const float* __restrict__ be, void* __restrict__ out)
{
    int row = blockIdx.x;
    int tid = threadIdx.x;
    const float2* rp = (const float2*)(in + (size_t)row * DD);
    float2 v = rp[tid];
    float s  = v.x + v.y;
    float ss = v.x * v.x + v.y * v.y;
#pragma unroll
    for (int off = 32; off > 0; off >>= 1) {
        s  += __shfl_xor(s, off);
        ss += __shfl_xor(ss, off);
    }
    __shared__ float sh[8];
    int wave = tid >> 6, lane = tid & 63;
    if (lane == 0) { sh[wave] = s; sh[4 + wave] = ss; }
    __syncthreads();
    float S  = sh[0] + sh[1] + sh[2] + sh[3];
    float SS = sh[4] + sh[5] + sh[6] + sh[7];
    float mean = S * (1.f / DD);
    float var  = SS * (1.f / DD) - mean * mean;
    var = fmaxf(var, 0.f);
    float rs = rsqrtf(var + 1e-5f);
    float2 gv = ((const float2*)g)[tid];
    float2 bv = ((const float2*)be)[tid];
    float ox = (v.x - mean) * rs * gv.x + bv.x;
    float oy = (v.y - mean) * rs * gv.y + bv.y;
    if (BF) {
        u32 w = (u32)f2b(ox) | ((u32)f2b(oy) << 16);
        ((u32*)out)[(size_t)row * (DD / 2) + tid] = w;
    } else {
        float2 o; o.x = ox; o.y = oy;
        ((float2*)out)[(size_t)row * (DD / 2) + tid] = o;
    }
}

extern "C" void kernel_launch(void* const* d_in, const int* in_sizes, int n_in,
                              void* d_out, int out_size, void* d_ws, size_t ws_size,
                              hipStream_t stream) {
    const float* nf     = (const float*)d_in[0];
    const int*   adj    = (const int*)d_in[1];
    const float* attn_w = (const float*)d_in[2];
    const float* attn_b = (const float*)d_in[3];
    const float* W1     = (const float*)d_in[4];
    const float* b1     = (const float*)d_in[5];
    const float* W2     = (const float*)d_in[6];
    const float* b2     = (const float*)d_in[7];
    const float* g1     = (const float*)d_in[8];
    const float* be1    = (const float*)d_in[9];
    const float* g2     = (const float*)d_in[10];
    const float* be2    = (const float*)d_in[11];
    float* out = (float*)d_out;

    char* wsb = (char*)d_ws;
    float* x_cur = (float*)(wsb);                      // 16 MB [0,16M)
    u16*   h_bf  = (u16*)(wsb + 16777216);             //  8 MB [16,24M)
    char*  scr   = wsb + 25165824;                     // 32 MB [24,56M)
    u16*   P     = (u16*)scr;                          //   [24,40M)
    float* hres  = (float*)(scr + 16777216);           //   [40,56M)
    u16*   mid   = (u16*)scr;                          //   [24,56M) after ln1 (P,hres dead)
    u16*   xT    = (u16*)(wsb + 58720256);             //  8 MB [56,64M)
    u16*   W1t   = (u16*)(wsb + 67108864);             //  6 MB [64,70M)
    u16*   W2t   = (u16*)(wsb + 73400320);             //  6 MB [70,76M)
    u64*   mask  = (u64*)(wsb + 79691776);             //  1 MB [76,77M)
    float* si    = (float*)(wsb + 80740352);           // 32 KB
    float* sj    = (float*)(wsb + 80773120);           // 32 KB

    // prep (re-done every call; cheap)
    mask_pack<<<512, 256, 0, stream>>>(adj, mask);
    transpose_cvt<<<dim3(64, 16, 3), 256, 0, stream>>>(W1, W1t, 512, 2048,
                                                       (size_t)512 * 2048, (size_t)512 * 2048);
    transpose_cvt<<<dim3(16, 64, 3), 256, 0, stream>>>(W2, W2t, 2048, 512,
                                                       (size_t)2048 * 512, (size_t)2048 * 512);

    for (int l = 0; l < 3; ++l) {
        const float* xin = (l == 0) ? nf : x_cur;
        score_proj_kernel<<<2048, 256, 0, stream>>>(xin, attn_w + (size_t)l * 1024, si, sj);
        transpose_cvt<<<dim3(16, 32, 8), 256, 0, stream>>>(xin, xT, 1024, 512,
                                                           (size_t)NN * DD, (size_t)NN * DD);
        softmax_p<<<1024, 256, 0, stream>>>(si, sj, attn_b + l, mask, P);
        // agg: hres[b] = P[b] @ x[b]^T + x[b]   (64x128 tiles, 512 blocks)
        gemm64<0><<<dim3(4, 16, 8), 256, 0, stream>>>(
            P, xT, nullptr, xin, hres, 1024, 512, 1024, 1024,
            (size_t)NN * NN, (size_t)DD * NN, (size_t)NN * DD, (size_t)NN * DD);
        // ln1 -> bf16 h
        ln_kernel<true><<<8192, 256, 0, stream>>>(hres, g1 + (size_t)l * 512, be1 + (size_t)l * 512, h_bf);
        // FFN1: mid = gelu(h @ W1 + b1)  (bf16 out; 128x128 tiles, 1024 blocks)
        gemm128<1><<<dim3(16, 64, 1), 256, 0, stream>>>(
            h_bf, W1t + (size_t)l * 1048576, b1 + (size_t)l * 2048, nullptr, mid,
            512, 2048, 512, 512, 0, 0, 0, 0);
        // FFN2: x_cur = mid @ W2 + b2 + h   (64x128 tiles, 512 blocks)
        gemm64<2><<<dim3(4, 128, 1), 256, 0, stream>>>(
            mid, W2t + (size_t)l * 1048576, b2 + (size_t)l * 512, h_bf, x_cur,
            2048, 512, 2048, 2048, 0, 0, 0, 0);
        void* lnout = (l == 2) ? (void*)out : (void*)x_cur;
        ln_kernel<false><<<8192, 256, 0, stream>>>(x_cur, g2 + (size_t)l * 512, be2 + (size_t)l * 512, lnout);
    }
}

// Round 5
// 475.966 us; speedup vs baseline: 7.1165x; 1.0652x over previous
//
#include <hip/hip_runtime.h>
#include <math.h>

#define NB 8
#define NN 1024
#define DD 512

typedef unsigned short u16;
typedef unsigned int u32;
typedef unsigned long long u64;
typedef __attribute__((ext_vector_type(8))) short bfrag;
typedef __attribute__((ext_vector_type(4))) float ffrag;

__device__ __forceinline__ u16 f2b(float f) {
    union { float f; u32 u; } v; v.f = f;
    u32 r = v.u + 0x7fffu + ((v.u >> 16) & 1u);   // RNE
    return (u16)(r >> 16);
}
__device__ __forceinline__ float b2f(u16 b) {
    union { u32 u; float f; } v; v.u = ((u32)b) << 16;
    return v.f;
}

// A&S 7.1.26 erf: |err| <= 1.5e-7
__device__ __forceinline__ float gelu_cheap(float v) {
    float s = v * 0.70710678118654752f;
    float a = fabsf(s);
    float t = 1.0f / (1.0f + 0.3275911f * a);
    float p = ((((1.061405429f * t - 1.453152027f) * t + 1.421413741f) * t
                - 0.284496736f) * t + 0.254829592f) * t;
    float erfa = 1.0f - p * __expf(-a * a);
    float erfs = copysignf(erfa, s);
    return 0.5f * v * (1.0f + erfs);
}

// async global->LDS, 16B per lane; lds base must be wave-uniform
__device__ __forceinline__ void gload_lds16(const void* g, void* l) {
    __builtin_amdgcn_global_load_lds(
        (const __attribute__((address_space(1))) void*)g,
        (__attribute__((address_space(3))) void*)l, 16, 0, 0);
}

// ---------------- mask pack: adj + diag -> bitmask [B*N][16] u64 -----------------
__global__ __launch_bounds__(256) void mask_pack(const int* __restrict__ adj,
                                                 u64* __restrict__ mb) {
    int idx = blockIdx.x * 256 + threadIdx.x;     // < 8*1024*16
    int w = idx & 15;
    int bi = idx >> 4;
    int i = bi & 1023;
    const int4* p = (const int4*)(adj + (size_t)bi * NN + w * 64);
    u64 m = 0;
#pragma unroll
    for (int q = 0; q < 16; ++q) {
        int4 v = p[q];
        if (v.x > 0) m |= 1ull << (q * 4 + 0);
        if (v.y > 0) m |= 1ull << (q * 4 + 1);
        if (v.z > 0) m |= 1ull << (q * 4 + 2);
        if (v.w > 0) m |= 1ull << (q * 4 + 3);
    }
    if (w == (i >> 6)) m |= 1ull << (i & 63);
    mb[idx] = m;
}

// ---------------- transpose + cvt: in fp32 [R][C] -> out bf16 [C][R] -------------
__global__ __launch_bounds__(256) void transpose_cvt(
    const float* __restrict__ in, u16* __restrict__ out,
    int R, int C, size_t inStr, size_t outStr)
{
    __shared__ float tile[32][33];
    int z = blockIdx.z;
    int r0 = blockIdx.y * 32, c0 = blockIdx.x * 32;
    int t = threadIdx.x;
    int tr = t >> 3, tc = (t & 7) * 4;
    float4 v = *(const float4*)(in + inStr * z + (size_t)(r0 + tr) * C + c0 + tc);
    tile[tr][tc + 0] = v.x; tile[tr][tc + 1] = v.y;
    tile[tr][tc + 2] = v.z; tile[tr][tc + 3] = v.w;
    __syncthreads();
    u32 w0 = (u32)f2b(tile[tc + 0][tr]) | ((u32)f2b(tile[tc + 1][tr]) << 16);
    u32 w1 = (u32)f2b(tile[tc + 2][tr]) | ((u32)f2b(tile[tc + 3][tr]) << 16);
    uint2 wv; wv.x = w0; wv.y = w1;
    *(uint2*)(out + outStr * z + (size_t)(c0 + tr) * R + r0 + tc) = wv;
}

// ---------------- score projection ----------------------------------------------
__global__ __launch_bounds__(256) void score_proj_kernel(
    const float* __restrict__ x, const float* __restrict__ w,
    float* __restrict__ si, float* __restrict__ sj)
{
    int wave = threadIdx.x >> 6;
    int lane = threadIdx.x & 63;
    int row = blockIdx.x * 4 + wave;
    const float4* xr = (const float4*)(x + (size_t)row * DD) + lane * 2;
    const float4* w1 = (const float4*)(w) + lane * 2;
    const float4* w2 = (const float4*)(w + DD) + lane * 2;
    float a = 0.f, b2 = 0.f;
#pragma unroll
    for (int c = 0; c < 2; ++c) {
        float4 xv = xr[c], wa = w1[c], wb = w2[c];
        a  += xv.x * wa.x + xv.y * wa.y + xv.z * wa.z + xv.w * wa.w;
        b2 += xv.x * wb.x + xv.y * wb.y + xv.z * wb.z + xv.w * wb.w;
    }
#pragma unroll
    for (int off = 32; off > 0; off >>= 1) {
        a  += __shfl_xor(a, off);
        b2 += __shfl_xor(b2, off);
    }
    if (lane == 0) { si[row] = a; sj[row] = b2; }
}

// ---------------- softmax -> P (bf16), register-resident -------------------------
__global__ __launch_bounds__(256) void softmax_p(
    const float* __restrict__ si, const float* __restrict__ sj,
    const float* __restrict__ attn_b, const u64* __restrict__ mb,
    u16* __restrict__ P)
{
    __shared__ u16 sb[8 * NN];        // 16 KB
    int b  = blockIdx.x >> 7;
    int i0 = (blockIdx.x & 127) * 8;
    int tid = threadIdx.x;
    int r = tid >> 5, l32 = tid & 31;
    int i = i0 + r;
    float bb = attn_b[0];
    float siv = si[b * NN + i];
    const float* sjb = sj + b * NN;
    const u64* mbr = mb + ((size_t)b * NN + i) * 16;

    float sv[32];
    float mx = -INFINITY;
#pragma unroll
    for (int q = 0; q < 32; ++q) {
        int j = q * 32 + l32;
        u64 w = mbr[q >> 1];
        int bit = ((q & 1) << 5) + l32;
        float s = siv + sjb[j] + bb;
        s = (s >= 0.f) ? s : 0.2f * s;
        s = ((w >> bit) & 1ull) ? s : -INFINITY;
        sv[q] = s;
        mx = fmaxf(mx, s);
    }
#pragma unroll
    for (int off = 16; off > 0; off >>= 1) mx = fmaxf(mx, __shfl_xor(mx, off, 32));
    float sum = 0.f;
#pragma unroll
    for (int q = 0; q < 32; ++q) {
        float p = __expf(sv[q] - mx);
        sv[q] = p;
        sum += p;
    }
#pragma unroll
    for (int off = 16; off > 0; off >>= 1) sum += __shfl_xor(sum, off, 32);
    float inv = 1.f / sum;
#pragma unroll
    for (int q = 0; q < 32; ++q)
        sb[r * NN + q * 32 + l32] = f2b(sv[q] * inv);
    __syncthreads();
    const uint4* src = (const uint4*)sb;
    uint4* dst = (uint4*)(P + ((size_t)b * NN + i0) * NN);
#pragma unroll
    for (int t = 0; t < 4; ++t) dst[t * 256 + tid] = src[t * 256 + tid];
}

// ======================= bf16 MFMA GEMM: 64x128 tile, BK=64, LDS double-buffer ===
// AITER-style pipeline: prefetch next tile's global_load_lds, then
// s_waitcnt vmcnt(6) (waits only current tile) + raw s_barrier — prefetch stays
// in flight across the barrier. XOR swizzle (col^row&7) folded into global addr.
// EPI: 0 = +res(fp32), fp32 out | 1 = +bias, gelu, bf16 out | 2 = +bias +res(bf16), fp32 out
template <int EPI>
__global__ __launch_bounds__(256) void gemm64(
    const u16* __restrict__ A, const u16* __restrict__ Bm,
    const float* __restrict__ bias, const void* __restrict__ res,
    void* __restrict__ Cout, int K, int N, int lda, int ldb,
    size_t aStr, size_t bStr, size_t cStr, size_t resStr)
{
    // layout (u16 elems): A buf0 [0,4096) buf1 [4096,8192); B buf0 [8192,16384) buf1 [16384,24576)
    __shared__ __align__(16) u16 lds[24576];   // 48 KB
    int z = blockIdx.z;
    int m0 = blockIdx.y * 64, n0 = blockIdx.x * 128;
    int tid = threadIdx.x;
    int lane = tid & 63, wv = tid >> 6;

    const u16* ag[2]; const u16* bg[4];
    u32 la[2], lb[4];
#pragma unroll
    for (int i = 0; i < 2; ++i) {
        int q = i * 256 + tid;
        int row = q >> 3, c = q & 7;
        ag[i] = A + aStr * z + (size_t)(m0 + row) * lda + (c ^ (row & 7)) * 8;
        la[i] = i * 2048 + wv * 512;
    }
#pragma unroll
    for (int i = 0; i < 4; ++i) {
        int q = i * 256 + tid;
        int row = q >> 3, c = q & 7;
        bg[i] = Bm + bStr * z + (size_t)(n0 + row) * ldb + (c ^ (row & 7)) * 8;
        lb[i] = 8192 + i * 2048 + wv * 512;
    }

    int mw = (wv >> 1) * 32, nw = (wv & 1) * 64;
    int lr = lane & 15, lq = lane >> 4;
    int sw = lr & 7;

    ffrag acc[2][4];
#pragma unroll
    for (int i = 0; i < 2; ++i)
#pragma unroll
        for (int j = 0; j < 4; ++j) acc[i][j] = (ffrag){0.f, 0.f, 0.f, 0.f};

    // prologue: stage k=0 into buf0
#pragma unroll
    for (int i = 0; i < 2; ++i) gload_lds16(ag[i], &lds[la[i]]);
#pragma unroll
    for (int i = 0; i < 4; ++i) gload_lds16(bg[i], &lds[lb[i]]);

    for (int k0 = 0; k0 < K; k0 += 64) {
        int cur = (k0 >> 6) & 1;
        if (k0 + 64 < K) {
            // prefetch next tile into other buffer (6 loads stay in flight)
#pragma unroll
            for (int i = 0; i < 2; ++i)
                gload_lds16(ag[i] + k0 + 64, &lds[((cur ^ 1) << 12) + la[i]]);
#pragma unroll
            for (int i = 0; i < 4; ++i)
                gload_lds16(bg[i] + k0 + 64, &lds[((cur ^ 1) << 13) + lb[i]]);
            asm volatile("s_waitcnt vmcnt(6)" ::: "memory");
        } else {
            asm volatile("s_waitcnt vmcnt(0)" ::: "memory");
        }
        asm volatile("s_barrier" ::: "memory");   // all waves: cur tile resident

        const u16* Ab = &lds[cur << 12];
        const u16* Bb = &lds[8192 + (cur << 13)];
#pragma unroll
        for (int h = 0; h < 2; ++h) {
            bfrag af[2], bf[4];
#pragma unroll
            for (int i = 0; i < 2; ++i)
                af[i] = *(const bfrag*)&Ab[(mw + i * 16 + lr) * 64 + ((h * 4 + lq) ^ sw) * 8];
#pragma unroll
            for (int j = 0; j < 4; ++j)
                bf[j] = *(const bfrag*)&Bb[(nw + j * 16 + lr) * 64 + ((h * 4 + lq) ^ sw) * 8];
#pragma unroll
            for (int i = 0; i < 2; ++i)
#pragma unroll
                for (int j = 0; j < 4; ++j)
                    acc[i][j] = __builtin_amdgcn_mfma_f32_16x16x32_bf16(af[i], bf[j], acc[i][j], 0, 0, 0);
        }
        // all waves done reading cur before next iter overwrites it
        asm volatile("s_waitcnt lgkmcnt(0)\ns_barrier" ::: "memory");
    }

    float* Cf = (float*)Cout + cStr * z;
    u16*   Cb = (u16*)Cout + cStr * z;
    const float* resf = (const float*)res;
    const u16*   resb = (const u16*)res;
#pragma unroll
    for (int i = 0; i < 2; ++i) {
        int row = m0 + mw + i * 16 + lq * 4;
#pragma unroll
        for (int j = 0; j < 4; ++j) {
            int col = n0 + nw + j * 16 + lr;
            float bv = (EPI != 0) ? bias[col] : 0.f;
#pragma unroll
            for (int r = 0; r < 4; ++r) {
                float v = acc[i][j][r] + bv;
                size_t off = (size_t)(row + r) * N + col;
                if (EPI == 1) {
                    Cb[off] = f2b(gelu_cheap(v));
                } else if (EPI == 0) {
                    Cf[off] = v + resf[resStr * z + off];
                } else {
                    Cf[off] = v + b2f(resb[off]);
                }
            }
        }
    }
}

// ---------------- layernorm over D=512, one row per block ------------------------
// BF=true: write bf16, else fp32
template <bool BF>
__global__ __launch_bounds__(256) void ln_kernel(
    const float* __restrict__ in, const float* __restrict__ g,
    const float* __restrict__ be, void* __restrict__ out)
{
    int row = blockIdx.x;
    int tid = threadIdx.x;
    const float2* rp = (const float2*)(in + (size_t)row * DD);
    float2 v = rp[tid];
    float s  = v.x + v.y;
    float ss = v.x * v.x + v.y * v.y;
#pragma unroll
    for (int off = 32; off > 0; off >>= 1) {
        s  += __shfl_xor(s, off);
        ss += __shfl_xor(ss, off);
    }
    __shared__ float sh[8];
    int wave = tid >> 6, lane = tid & 63;
    if (lane == 0) { sh[wave] = s; sh[4 + wave] = ss; }
    __syncthreads();
    float S  = sh[0] + sh[1] + sh[2] + sh[3];
    float SS = sh[4] + sh[5] + sh[6] + sh[7];
    float mean = S * (1.f / DD);
    float var  = SS * (1.f / DD) - mean * mean;
    var = fmaxf(var, 0.f);
    float rs = rsqrtf(var + 1e-5f);
    float2 gv = ((const float2*)g)[tid];
    float2 bv = ((const float2*)be)[tid];
    float ox = (v.x - mean) * rs * gv.x + bv.x;
    float oy = (v.y - mean) * rs * gv.y + bv.y;
    if (BF) {
        u32 w = (u32)f2b(ox) | ((u32)f2b(oy) << 16);
        ((u32*)out)[(size_t)row * (DD / 2) + tid] = w;
    } else {
        float2 o; o.x = ox; o.y = oy;
        ((float2*)out)[(size_t)row * (DD / 2) + tid] = o;
    }
}

extern "C" void kernel_launch(void* const* d_in, const int* in_sizes, int n_in,
                              void* d_out, int out_size, void* d_ws, size_t ws_size,
                              hipStream_t stream) {
    const float* nf     = (const float*)d_in[0];
    const int*   adj    = (const int*)d_in[1];
    const float* attn_w = (const float*)d_in[2];
    const float* attn_b = (const float*)d_in[3];
    const float* W1     = (const float*)d_in[4];
    const float* b1     = (const float*)d_in[5];
    const float* W2     = (const float*)d_in[6];
    const float* b2     = (const float*)d_in[7];
    const float* g1     = (const float*)d_in[8];
    const float* be1    = (const float*)d_in[9];
    const float* g2     = (const float*)d_in[10];
    const float* be2    = (const float*)d_in[11];
    float* out = (float*)d_out;

    char* wsb = (char*)d_ws;
    float* x_cur = (float*)(wsb);                      // 16 MB [0,16M)
    u16*   h_bf  = (u16*)(wsb + 16777216);             //  8 MB [16,24M)
    char*  scr   = wsb + 25165824;                     // 32 MB [24,56M)
    u16*   P     = (u16*)scr;                          //   [24,40M)
    float* hres  = (float*)(scr + 16777216);           //   [40,56M)
    u16*   mid   = (u16*)scr;                          //   [24,56M) after ln1 (P,hres dead)
    u16*   xT    = (u16*)(wsb + 58720256);             //  8 MB [56,64M)
    u16*   W1t   = (u16*)(wsb + 67108864);             //  6 MB [64,70M)
    u16*   W2t   = (u16*)(wsb + 73400320);             //  6 MB [70,76M)
    u64*   mask  = (u64*)(wsb + 79691776);             //  1 MB [76,77M)
    float* si    = (float*)(wsb + 80740352);           // 32 KB
    float* sj    = (float*)(wsb + 80773120);           // 32 KB

    // prep (re-done every call; cheap)
    mask_pack<<<512, 256, 0, stream>>>(adj, mask);
    transpose_cvt<<<dim3(64, 16, 3), 256, 0, stream>>>(W1, W1t, 512, 2048,
                                                       (size_t)512 * 2048, (size_t)512 * 2048);
    transpose_cvt<<<dim3(16, 64, 3), 256, 0, stream>>>(W2, W2t, 2048, 512,
                                                       (size_t)2048 * 512, (size_t)2048 * 512);

    for (int l = 0; l < 3; ++l) {
        const float* xin = (l == 0) ? nf : x_cur;
        score_proj_kernel<<<2048, 256, 0, stream>>>(xin, attn_w + (size_t)l * 1024, si, sj);
        transpose_cvt<<<dim3(16, 32, 8), 256, 0, stream>>>(xin, xT, 1024, 512,
                                                           (size_t)NN * DD, (size_t)NN * DD);
        softmax_p<<<1024, 256, 0, stream>>>(si, sj, attn_b + l, mask, P);
        // agg: hres[b] = P[b] @ x[b]^T + x[b]   (64x128 tiles, 512 blocks, K=1024)
        gemm64<0><<<dim3(4, 16, 8), 256, 0, stream>>>(
            P, xT, nullptr, xin, hres, 1024, 512, 1024, 1024,
            (size_t)NN * NN, (size_t)DD * NN, (size_t)NN * DD, (size_t)NN * DD);
        // ln1 -> bf16 h
        ln_kernel<true><<<8192, 256, 0, stream>>>(hres, g1 + (size_t)l * 512, be1 + (size_t)l * 512, h_bf);
        // FFN1: mid = gelu(h @ W1 + b1)  (bf16 out; 2048 blocks, K=512)
        gemm64<1><<<dim3(16, 128, 1), 256, 0, stream>>>(
            h_bf, W1t + (size_t)l * 1048576, b1 + (size_t)l * 2048, nullptr, mid,
            512, 2048, 512, 512, 0, 0, 0, 0);
        // FFN2: x_cur = mid @ W2 + b2 + h   (512 blocks, K=2048)
        gemm64<2><<<dim3(4, 128, 1), 256, 0, stream>>>(
            mid, W2t + (size_t)l * 1048576, b2 + (size_t)l * 512, h_bf, x_cur,
            2048, 512, 2048, 2048, 0, 0, 0, 0);
        void* lnout = (l == 2) ? (void*)out : (void*)x_cur;
        ln_kernel<false><<<8192, 256, 0, stream>>>(x_cur, g2 + (size_t)l * 512, be2 + (size_t)l * 512, lnout);
    }
}